// Round 1
// baseline (354.449 us; speedup 1.0000x reference)
//
#include <hip/hip_runtime.h>

// RmiModel: per-batch IMU preintegration.
// x: (B, 7, N) f32; ch0 = t, ch1..6 = raw imu. calib: (6,6), bias: (6,).
// out: (B, 15) = [DR(3), DV(3), DC(9 row-major)].
//
// Strategy: 4 segments per batch (preintegration composes), 256-thr blocks =
// 64 batches x 4 segments -> 2048 waves total (8 waves/CU). float4 chunked
// loads (segment starts multiple of 4 -> 16B aligned). Combine segments in LDS,
// stage output in LDS, coalesced store.

constexpr int N      = 200;
constexpr int NSTEP  = N - 1;   // 199 scan steps
constexpr int SEGLEN = 52;      // multiple of 4; last segment = 199-156 = 43
constexpr int BPB    = 64;      // batches per block
constexpr int TPB    = 256;     // BPB * 4 segments

__device__ __forceinline__ float f4e(const float4& v, int j) {
    return j == 0 ? v.x : j == 1 ? v.y : j == 2 ? v.z : v.w;
}

__global__ __launch_bounds__(TPB) void rmi_kernel(
    const float* __restrict__ x, const float* __restrict__ calib,
    const float* __restrict__ bias, float* __restrict__ out, int Bn)
{
    const int tid = threadIdx.x;
    const int lb  = tid >> 2;   // local batch 0..63
    const int sg  = tid & 3;    // segment 0..3
    int b = blockIdx.x * BPB + lb;
    if (b >= Bn) b = Bn - 1;    // clamp; output write is guarded

    // M = I6 + calib, bias. Uniform addresses -> expect SGPR residency.
    float M[6][6], bi[6];
#pragma unroll
    for (int i = 0; i < 6; ++i) {
        bi[i] = bias[i];
#pragma unroll
        for (int j = 0; j < 6; ++j)
            M[i][j] = calib[i * 6 + j] + (i == j ? 1.0f : 0.0f);
    }

    const int start = sg * SEGLEN;                       // 0,52,104,156
    const int end   = (sg == 3) ? NSTEP : start + SEGLEN; // exclusive step bound
    const int nch   = (end - start + 3) >> 2;            // 13,13,13,11

    const float* row = x + (size_t)b * (7 * N);          // channel 0 = t

    float DR[3] = {0.f, 0.f, 0.f}, DV[3] = {0.f, 0.f, 0.f};
    float C[3][3] = {{1.f,0.f,0.f},{0.f,1.f,0.f},{0.f,0.f,1.f}};
    float T = 0.f;

    for (int k = 0; k < nch; ++k) {
        const int base = start + 4 * k;
        float4 tv = *reinterpret_cast<const float4*>(row + base);
        // t[base+4]: always within this batch's rows (base+4 <= 200), value
        // only consumed when it is a real t (j==3 step executes => n+1 <= end-? yes <= end).
        float tnext = row[base + 4];
        float4 ch[6];
#pragma unroll
        for (int c = 0; c < 6; ++c)
            ch[c] = *reinterpret_cast<const float4*>(row + (c + 1) * N + base);

        // x1 = (I+calib) @ raw + bias, vectorized over the 4 steps of the chunk
        float4 y[6];
#pragma unroll
        for (int i = 0; i < 6; ++i) {
            float4 acc = make_float4(bi[i], bi[i], bi[i], bi[i]);
#pragma unroll
            for (int j = 0; j < 6; ++j) {
                acc.x += M[i][j] * ch[j].x;
                acc.y += M[i][j] * ch[j].y;
                acc.z += M[i][j] * ch[j].z;
                acc.w += M[i][j] * ch[j].w;
            }
            y[i] = acc;
        }

#pragma unroll
        for (int j = 0; j < 4; ++j) {
            const int n = base + j;
            if (n < end) {
                float tn  = f4e(tv, j);
                float tn1 = (j < 3) ? f4e(tv, j + 1) : tnext;
                float dt  = tn1 - tn;
                float gx = f4e(y[0], j), gy = f4e(y[1], j), gz = f4e(y[2], j);
                float ax = f4e(y[3], j), ay = f4e(y[4], j), az = f4e(y[5], j);
                // Ca = C @ a (pre-update C)
                float c0 = C[0][0]*ax + C[0][1]*ay + C[0][2]*az;
                float c1 = C[1][0]*ax + C[1][1]*ay + C[1][2]*az;
                float c2 = C[2][0]*ax + C[2][1]*ay + C[2][2]*az;
                float h = 0.5f * dt * dt;
                DR[0] += DV[0]*dt + c0*h;
                DR[1] += DV[1]*dt + c1*h;
                DR[2] += DV[2]*dt + c2*h;
                DV[0] += c0*dt; DV[1] += c1*dt; DV[2] += c2*dt;
                T += dt;
                // so3_exp(g*dt), matching reference branch semantics
                float px = gx*dt, py = gy*dt, pz = gz*dt;
                float t2 = px*px + py*py + pz*pz;
                bool  sm = t2 < 1e-8f;
                float t2s = sm ? 1.0f : t2;
                float th = sqrtf(t2s);
                float sn = sinf(th), cs = cosf(th);
                float A  = sm ? (1.0f - t2 * (1.0f/6.0f))  : (sn / th);
                float Bc = sm ? (0.5f - t2 * (1.0f/24.0f)) : ((1.0f - cs) / t2s);
                float xx = px*px, yy = py*py, zz = pz*pz;
                float xy = px*py, xz = px*pz, yz = py*pz;
                float E00 = 1.0f - Bc*(yy+zz), E01 = Bc*xy - A*pz, E02 = Bc*xz + A*py;
                float E10 = Bc*xy + A*pz, E11 = 1.0f - Bc*(xx+zz), E12 = Bc*yz - A*px;
                float E20 = Bc*xz - A*py, E21 = Bc*yz + A*px, E22 = 1.0f - Bc*(xx+yy);
                // C = C @ E
                float n00 = C[0][0]*E00 + C[0][1]*E10 + C[0][2]*E20;
                float n01 = C[0][0]*E01 + C[0][1]*E11 + C[0][2]*E21;
                float n02 = C[0][0]*E02 + C[0][1]*E12 + C[0][2]*E22;
                float n10 = C[1][0]*E00 + C[1][1]*E10 + C[1][2]*E20;
                float n11 = C[1][0]*E01 + C[1][1]*E11 + C[1][2]*E21;
                float n12 = C[1][0]*E02 + C[1][1]*E12 + C[1][2]*E22;
                float n20 = C[2][0]*E00 + C[2][1]*E10 + C[2][2]*E20;
                float n21 = C[2][0]*E01 + C[2][1]*E11 + C[2][2]*E21;
                float n22 = C[2][0]*E02 + C[2][1]*E12 + C[2][2]*E22;
                C[0][0]=n00; C[0][1]=n01; C[0][2]=n02;
                C[1][0]=n10; C[1][1]=n11; C[1][2]=n12;
                C[2][0]=n20; C[2][1]=n21; C[2][2]=n22;
            }
        }
    }

    // --- combine 4 segments per batch via LDS ---
    __shared__ float segb[TPB][17];   // 16 payload + 1 pad (odd stride -> no bank conflict)
    segb[tid][0]  = DR[0]; segb[tid][1]  = DR[1]; segb[tid][2]  = DR[2];
    segb[tid][3]  = DV[0]; segb[tid][4]  = DV[1]; segb[tid][5]  = DV[2];
    segb[tid][6]  = C[0][0]; segb[tid][7]  = C[0][1]; segb[tid][8]  = C[0][2];
    segb[tid][9]  = C[1][0]; segb[tid][10] = C[1][1]; segb[tid][11] = C[1][2];
    segb[tid][12] = C[2][0]; segb[tid][13] = C[2][1]; segb[tid][14] = C[2][2];
    segb[tid][15] = T;
    __syncthreads();

    __shared__ float ostage[BPB * 15];
    if (sg == 0) {
        float R[3] = {0.f,0.f,0.f}, V[3] = {0.f,0.f,0.f};
        float Cc[3][3] = {{1.f,0.f,0.f},{0.f,1.f,0.f},{0.f,0.f,1.f}};
#pragma unroll
        for (int ss = 0; ss < 4; ++ss) {
            const float* p = segb[lb * 4 + ss];
            float Ts = p[15];
#pragma unroll
            for (int i = 0; i < 3; ++i) {
                float ri = Cc[i][0]*p[0] + Cc[i][1]*p[1] + Cc[i][2]*p[2];
                float vi = Cc[i][0]*p[3] + Cc[i][1]*p[4] + Cc[i][2]*p[5];
                R[i] += V[i]*Ts + ri;   // uses pre-update V and Cc
                V[i] += vi;
            }
            float Nc[3][3];
#pragma unroll
            for (int i = 0; i < 3; ++i)
#pragma unroll
                for (int j2 = 0; j2 < 3; ++j2)
                    Nc[i][j2] = Cc[i][0]*p[6+j2] + Cc[i][1]*p[9+j2] + Cc[i][2]*p[12+j2];
#pragma unroll
            for (int i = 0; i < 3; ++i)
#pragma unroll
                for (int j2 = 0; j2 < 3; ++j2)
                    Cc[i][j2] = Nc[i][j2];
        }
        float* o = &ostage[lb * 15];
        o[0] = R[0];  o[1] = R[1];  o[2] = R[2];
        o[3] = V[0];  o[4] = V[1];  o[5] = V[2];
        o[6]  = Cc[0][0]; o[7]  = Cc[0][1]; o[8]  = Cc[0][2];
        o[9]  = Cc[1][0]; o[10] = Cc[1][1]; o[11] = Cc[1][2];
        o[12] = Cc[2][0]; o[13] = Cc[2][1]; o[14] = Cc[2][2];
    }
    __syncthreads();

    const int obase = blockIdx.x * (BPB * 15);
    for (int i = tid; i < BPB * 15; i += TPB) {
        int oi = obase + i;
        if (oi < Bn * 15) out[oi] = ostage[i];
    }
}

extern "C" void kernel_launch(void* const* d_in, const int* in_sizes, int n_in,
                              void* d_out, int out_size, void* d_ws, size_t ws_size,
                              hipStream_t stream) {
    const float* x     = (const float*)d_in[0];
    const float* calib = (const float*)d_in[1];
    const float* bias  = (const float*)d_in[2];
    float* out = (float*)d_out;
    const int Bn = in_sizes[0] / (7 * N);
    const int blocks = (Bn + BPB - 1) / BPB;
    rmi_kernel<<<blocks, TPB, 0, stream>>>(x, calib, bias, out, Bn);
}

// Round 2
// 74.891 us; speedup vs baseline: 4.7329x; 4.7329x over previous
//
#include <hip/hip_runtime.h>

// RmiModel: per-batch IMU preintegration, wave-per-batch formulation.
// x: (B, 7, N) f32; ch0 = t, ch1..6 = raw imu. calib: (6,6), bias: (6,).
// out: (B, 15) = [DR(3), DV(3), DC(9 row-major)].
//
// One 64-lane wave per batch. Lane l owns scan steps 4l..4l+3 and loads its
// own float4 per channel -> wave reads 1KB contiguous per channel (perfectly
// coalesced, every fetched line fully consumed). Each lane computes its
// 4-step segment transform (R,V,C,T) from identity; a 6-round shfl_xor
// butterfly composes the 64 ordered segments (preintegration semigroup).

constexpr int N     = 200;
constexpr int NSTEP = N - 1;   // 199
constexpr int WPB   = 4;       // waves (batches) per block
constexpr int TPB   = 64 * WPB;

__device__ __forceinline__ float f4e(const float4& v, int j) {
    return j == 0 ? v.x : j == 1 ? v.y : j == 2 ? v.z : v.w;
}

struct Seg { float R[3], V[3], C[9], T; };

// a followed by b
__device__ __forceinline__ Seg compose(const Seg& a, const Seg& b) {
    Seg o;
    o.T = a.T + b.T;
#pragma unroll
    for (int i = 0; i < 3; ++i) {
        const float ai0 = a.C[3*i], ai1 = a.C[3*i+1], ai2 = a.C[3*i+2];
        o.R[i] = a.R[i] + a.V[i] * b.T + ai0*b.R[0] + ai1*b.R[1] + ai2*b.R[2];
        o.V[i] = a.V[i]             + ai0*b.V[0] + ai1*b.V[1] + ai2*b.V[2];
#pragma unroll
        for (int j = 0; j < 3; ++j)
            o.C[3*i+j] = ai0*b.C[j] + ai1*b.C[3+j] + ai2*b.C[6+j];
    }
    return o;
}

__global__ __launch_bounds__(TPB) void rmi_kernel(
    const float* __restrict__ x, const float* __restrict__ calib,
    const float* __restrict__ bias, float* __restrict__ out, int Bn)
{
    const int tid  = threadIdx.x;
    const int lane = tid & 63;
    const int wv   = tid >> 6;
    int b = blockIdx.x * WPB + wv;
    if (b >= Bn) b = Bn - 1;               // clamp; final write guarded

    const float* row = x + (size_t)b * (7 * N);

    // lane l owns steps 4l..4l+3; lanes >= 50 clamp to row head (cached line,
    // no extra HBM fetch, results predicated off)
    const int off = (lane <= 49) ? 4 * lane : 0;

    float4 tv = *reinterpret_cast<const float4*>(row + off);
    float4 ch[6];
#pragma unroll
    for (int c = 0; c < 6; ++c)
        ch[c] = *reinterpret_cast<const float4*>(row + (c + 1) * N + off);
    const float tnext = __shfl_down(tv.x, 1);   // t[4l+4] (unused by lane 49)

    // M = I6 + calib, bias: uniform addresses -> scalar regs
    float M[6][6], bi[6];
#pragma unroll
    for (int i = 0; i < 6; ++i) {
        bi[i] = bias[i];
#pragma unroll
        for (int j = 0; j < 6; ++j)
            M[i][j] = calib[i * 6 + j] + (i == j ? 1.0f : 0.0f);
    }

    // calibrate the 4 owned samples: y = M @ raw + bias
    float4 y[6];
#pragma unroll
    for (int i = 0; i < 6; ++i) {
        float4 acc = make_float4(bi[i], bi[i], bi[i], bi[i]);
#pragma unroll
        for (int j = 0; j < 6; ++j) {
            acc.x += M[i][j] * ch[j].x;
            acc.y += M[i][j] * ch[j].y;
            acc.z += M[i][j] * ch[j].z;
            acc.w += M[i][j] * ch[j].w;
        }
        y[i] = acc;
    }

    // per-lane segment transform from identity
    Seg s;
    s.R[0]=s.R[1]=s.R[2]=0.f; s.V[0]=s.V[1]=s.V[2]=0.f; s.T=0.f;
    s.C[0]=1.f; s.C[1]=0.f; s.C[2]=0.f;
    s.C[3]=0.f; s.C[4]=1.f; s.C[5]=0.f;
    s.C[6]=0.f; s.C[7]=0.f; s.C[8]=1.f;

#pragma unroll
    for (int j = 0; j < 4; ++j) {
        const int n = 4 * lane + j;
        if (lane <= 49 && n < NSTEP) {
            float tn  = f4e(tv, j);
            float tn1 = (j < 3) ? f4e(tv, j + 1) : tnext;
            float dt  = tn1 - tn;
            float gx = f4e(y[0], j), gy = f4e(y[1], j), gz = f4e(y[2], j);
            float ax = f4e(y[3], j), ay = f4e(y[4], j), az = f4e(y[5], j);
            float c0 = s.C[0]*ax + s.C[1]*ay + s.C[2]*az;
            float c1 = s.C[3]*ax + s.C[4]*ay + s.C[5]*az;
            float c2 = s.C[6]*ax + s.C[7]*ay + s.C[8]*az;
            float h = 0.5f * dt * dt;
            s.R[0] += s.V[0]*dt + c0*h;
            s.R[1] += s.V[1]*dt + c1*h;
            s.R[2] += s.V[2]*dt + c2*h;
            s.V[0] += c0*dt; s.V[1] += c1*dt; s.V[2] += c2*dt;
            s.T += dt;
            // so3_exp(g*dt)
            float px = gx*dt, py = gy*dt, pz = gz*dt;
            float t2 = px*px + py*py + pz*pz;
            bool  sm = t2 < 1e-8f;
            float t2s = sm ? 1.0f : t2;
            float th = sqrtf(t2s);
            float sn = __sinf(th), cs = __cosf(th);
            float A  = sm ? (1.0f - t2 * (1.0f/6.0f))  : __fdividef(sn, th);
            float Bc = sm ? (0.5f - t2 * (1.0f/24.0f)) : __fdividef(1.0f - cs, t2s);
            float xx = px*px, yy = py*py, zz = pz*pz;
            float xy = px*py, xz = px*pz, yz = py*pz;
            float E00 = 1.0f - Bc*(yy+zz), E01 = Bc*xy - A*pz, E02 = Bc*xz + A*py;
            float E10 = Bc*xy + A*pz, E11 = 1.0f - Bc*(xx+zz), E12 = Bc*yz - A*px;
            float E20 = Bc*xz - A*py, E21 = Bc*yz + A*px, E22 = 1.0f - Bc*(xx+yy);
            float n0 = s.C[0]*E00 + s.C[1]*E10 + s.C[2]*E20;
            float n1 = s.C[0]*E01 + s.C[1]*E11 + s.C[2]*E21;
            float n2 = s.C[0]*E02 + s.C[1]*E12 + s.C[2]*E22;
            float n3 = s.C[3]*E00 + s.C[4]*E10 + s.C[5]*E20;
            float n4 = s.C[3]*E01 + s.C[4]*E11 + s.C[5]*E21;
            float n5 = s.C[3]*E02 + s.C[4]*E12 + s.C[5]*E22;
            float n6 = s.C[6]*E00 + s.C[7]*E10 + s.C[8]*E20;
            float n7 = s.C[6]*E01 + s.C[7]*E11 + s.C[8]*E21;
            float n8 = s.C[6]*E02 + s.C[7]*E12 + s.C[8]*E22;
            s.C[0]=n0; s.C[1]=n1; s.C[2]=n2;
            s.C[3]=n3; s.C[4]=n4; s.C[5]=n5;
            s.C[6]=n6; s.C[7]=n7; s.C[8]=n8;
        }
    }

    // ordered butterfly all-reduce over the non-commutative semigroup
#pragma unroll
    for (int r = 0; r < 6; ++r) {
        const int d = 1 << r;
        Seg o;
        o.T = __shfl_xor(s.T, d);
#pragma unroll
        for (int i = 0; i < 3; ++i) { o.R[i] = __shfl_xor(s.R[i], d); o.V[i] = __shfl_xor(s.V[i], d); }
#pragma unroll
        for (int i = 0; i < 9; ++i) o.C[i] = __shfl_xor(s.C[i], d);
        const bool lower = ((lane >> r) & 1) == 0;   // my block precedes partner's
        Seg a, c;
#pragma unroll
        for (int i = 0; i < 3; ++i) {
            a.R[i] = lower ? s.R[i] : o.R[i];  c.R[i] = lower ? o.R[i] : s.R[i];
            a.V[i] = lower ? s.V[i] : o.V[i];  c.V[i] = lower ? o.V[i] : s.V[i];
        }
#pragma unroll
        for (int i = 0; i < 9; ++i) { a.C[i] = lower ? s.C[i] : o.C[i]; c.C[i] = lower ? o.C[i] : s.C[i]; }
        a.T = lower ? s.T : o.T;  c.T = lower ? o.T : s.T;
        s = compose(a, c);
    }

    // stage per-block outputs in LDS, write coalesced
    __shared__ float os[WPB][15];
    if (lane == 0) {
        os[wv][0]  = s.R[0]; os[wv][1]  = s.R[1]; os[wv][2]  = s.R[2];
        os[wv][3]  = s.V[0]; os[wv][4]  = s.V[1]; os[wv][5]  = s.V[2];
#pragma unroll
        for (int i = 0; i < 9; ++i) os[wv][6 + i] = s.C[i];
    }
    __syncthreads();
    if (tid < WPB * 15) {
        const int ob = blockIdx.x * WPB + tid / 15;
        if (ob < Bn) out[(size_t)ob * 15 + tid % 15] = os[tid / 15][tid % 15];
    }
}

extern "C" void kernel_launch(void* const* d_in, const int* in_sizes, int n_in,
                              void* d_out, int out_size, void* d_ws, size_t ws_size,
                              hipStream_t stream) {
    const float* x     = (const float*)d_in[0];
    const float* calib = (const float*)d_in[1];
    const float* bias  = (const float*)d_in[2];
    float* out = (float*)d_out;
    const int Bn = in_sizes[0] / (7 * N);
    const int blocks = (Bn + WPB - 1) / WPB;
    rmi_kernel<<<blocks, TPB, 0, stream>>>(x, calib, bias, out, Bn);
}